// Round 1
// 175.691 us; speedup vs baseline: 1.4682x; 1.4682x over previous
//
#include <hip/hip_runtime.h>
#include <math.h>

typedef _Float16 f16;
typedef __attribute__((ext_vector_type(8))) f16 f16x8;
typedef __attribute__((ext_vector_type(2))) f16 f16x2;
typedef __attribute__((ext_vector_type(4))) float f32x4;
typedef __attribute__((ext_vector_type(4))) int   i32x4;

__device__ __forceinline__ short f2h(float f) {      // RNE f32->f16, bits
    return __builtin_bit_cast(short, (f16)f);
}
__device__ __forceinline__ float h2f(short s) {
    return (float)__builtin_bit_cast(f16, s);
}

__device__ __forceinline__ void gload16(const void* g, void* l) {
    __builtin_amdgcn_global_load_lds(
        (const __attribute__((address_space(1))) unsigned int*)g,
        (__attribute__((address_space(3))) unsigned int*)l, 16, 0, 0);
}

#define MFMA16(A, B, C) __builtin_amdgcn_mfma_f32_16x16x32_f16(A, B, C, 0, 0, 0)

// ---------------------------------------------------------------------------
// fp32 -> single f16 conversion. Segments (float4 units): q 524288 |
// kv 1048576 | Wq,Wk,Wv,Wo 65536 each. Thread = one float4.
// ---------------------------------------------------------------------------
__global__ __launch_bounds__(256) void convert_kernel(
    const float* __restrict__ q, const float* __restrict__ kv,
    const float* __restrict__ Wq, const float* __restrict__ Wk,
    const float* __restrict__ Wv, const float* __restrict__ Wo,
    short* __restrict__ cq, short* __restrict__ ckv,
    short* __restrict__ wq, short* __restrict__ wk,
    short* __restrict__ wv, short* __restrict__ wo)
{
    int g = blockIdx.x * 256 + threadIdx.x;
    const float* src; short* dst; int local;
    if      (g <  524288) { src = q;  dst = cq;  local = g; }
    else if (g < 1572864) { src = kv; dst = ckv; local = g -  524288; }
    else if (g < 1638400) { src = Wq; dst = wq;  local = g - 1572864; }
    else if (g < 1703936) { src = Wk; dst = wk;  local = g - 1638400; }
    else if (g < 1769472) { src = Wv; dst = wv;  local = g - 1703936; }
    else                  { src = Wo; dst = wo;  local = g - 1769472; }
    float4 v = *(const float4*)(src + (size_t)local * 4);
    short4 hv; short* hp = (short*)&hv;
    hp[0] = f2h(v.x); hp[1] = f2h(v.y); hp[2] = f2h(v.z); hp[3] = f2h(v.w);
    *(short4*)(dst + (size_t)local * 4) = hv;
}

// ---------------------------------------------------------------------------
// Single-pass f16 GEMM core: Y[m][n] = sum_k X[m][k] W[n][k] + bias[n].
// RT = rows per block (128 or 64), 128 cols, 4 waves (2x2), BK=32,
// global_load_lds staging. EP: 0 fp32 out | 1 f16 out scaled | 2 V-frag out.
// ---------------------------------------------------------------------------
template<int RT, int EP>
__device__ __forceinline__ void gemm_core(
    short* As, short* Bs,
    const short* __restrict__ X, const short* __restrict__ W,
    const float* __restrict__ bias, float scale,
    float* __restrict__ outF, short* __restrict__ outH,
    int m0, int n0)
{
    const int tid  = threadIdx.x;
    const int wave = tid >> 6, lane = tid & 63;
    const int quad = lane >> 4, col = lane & 15;
    const int wy = wave >> 1, wx = wave & 1;
    constexpr int MT = RT / 32;          // per-wave 16-row m-tiles

    f32x4 acc[MT][4];
    #pragma unroll
    for (int i = 0; i < MT; ++i)
        #pragma unroll
        for (int j = 0; j < 4; ++j) acc[i][j] = (f32x4){0.f, 0.f, 0.f, 0.f};

    int aoff[MT], boff[4];
    #pragma unroll
    for (int t = 0; t < MT; ++t)
        aoff[t] = (wy * (RT / 2) + t * 16 + col) * 32 + quad * 8;
    #pragma unroll
    for (int t = 0; t < 4; ++t)
        boff[t] = (wx * 64 + t * 16 + col) * 32 + quad * 8;

    const short* Abase = X + (size_t)m0 * 512;
    const short* Bbase = W + (size_t)n0 * 512;

    for (int kb = 0; kb < 512; kb += 32) {
        __syncthreads();
        #pragma unroll
        for (int i = 0; i < RT / 64; ++i) {
            int p = i * 256 + tid;
            int r = p >> 2, qq = p & 3;
            gload16(Abase + (size_t)r * 512 + kb + qq * 8,
                    &As[(i * 256 + wave * 64) * 8]);
        }
        #pragma unroll
        for (int i = 0; i < 2; ++i) {
            int p = i * 256 + tid;
            int r = p >> 2, qq = p & 3;
            gload16(Bbase + (size_t)r * 512 + kb + qq * 8,
                    &Bs[(i * 256 + wave * 64) * 8]);
        }
        __syncthreads();   // drains vmcnt(0): staged data visible

        f16x8 a[MT], b[4];
        #pragma unroll
        for (int t = 0; t < MT; ++t) a[t] = *(const f16x8*)&As[aoff[t]];
        #pragma unroll
        for (int t = 0; t < 4; ++t)  b[t] = *(const f16x8*)&Bs[boff[t]];
        #pragma unroll
        for (int tm = 0; tm < MT; ++tm)
            #pragma unroll
            for (int tn = 0; tn < 4; ++tn)
                acc[tm][tn] = MFMA16(a[tm], b[tn], acc[tm][tn]);
    }

    #pragma unroll
    for (int tn = 0; tn < 4; ++tn) {
        int ng = n0 + wx * 64 + tn * 16 + col;
        float bb = bias[ng];
        #pragma unroll
        for (int tm = 0; tm < MT; ++tm) {
            int mb = m0 + wy * (RT / 2) + tm * 16 + quad * 4;
            if constexpr (EP == 2) {
                // V-fragment order for attention PV B-operand.
                int bb_ = mb >> 12, kvg = mb & 4095;
                int tile = kvg >> 7, kv128 = kvg & 127;
                int t01 = (kv128 >> 6) & 1, sv = (kv128 >> 4) & 3, qd = (kv128 >> 2) & 3;
                int hh = ng >> 6, dd = ng & 63, dt = dd >> 4, d15 = dd & 15;
                size_t base = ((((size_t)((bb_ * 8 + hh) * 32 + tile) * 16)
                               + sv * 4 + dt) * 64 + qd * 16 + d15) * 8 + t01 * 4;
                short4 s4; short* sp = (short*)&s4;
                #pragma unroll
                for (int r = 0; r < 4; ++r) sp[r] = f2h(acc[tm][tn][r] + bb);
                *(short4*)&outH[base] = s4;
            } else if constexpr (EP == 1) {
                #pragma unroll
                for (int r = 0; r < 4; ++r)
                    outH[(size_t)(mb + r) * 512 + ng] =
                        f2h((acc[tm][tn][r] + bb) * scale);
            } else {
                #pragma unroll
                for (int r = 0; r < 4; ++r)
                    outF[(size_t)(mb + r) * 512 + ng] = acc[tm][tn][r] + bb;
            }
        }
    }
}

// Fused Q/K/V projections: blocks [0,128) Q | [128,384) K | [384,640) V.
__global__ __launch_bounds__(256) void fused_qkv_gemm_kernel(
    const short* __restrict__ cq, const short* __restrict__ ckv,
    const short* __restrict__ wq, const short* __restrict__ wk,
    const short* __restrict__ wv,
    const float* __restrict__ bq, const float* __restrict__ bk,
    const float* __restrict__ bv, float qscale,
    short* __restrict__ Qh, short* __restrict__ Kh, short* __restrict__ Vf)
{
    __shared__ short As[128 * 32], Bs[128 * 32];
    int bi = blockIdx.x;
    if (bi < 128) {
        gemm_core<128, 1>(As, Bs, cq, wq, bq, qscale, nullptr, Qh,
                          (bi >> 2) * 128, (bi & 3) * 128);
    } else if (bi < 384) {
        bi -= 128;
        gemm_core<128, 1>(As, Bs, ckv, wk, bk, 1.0f, nullptr, Kh,
                          (bi >> 2) * 128, (bi & 3) * 128);
    } else {
        bi -= 384;
        gemm_core<128, 2>(As, Bs, ckv, wv, bv, 1.0f, nullptr, Vf,
                          (bi >> 2) * 128, (bi & 3) * 128);
    }
}

// O-projection: 64-row tiles -> 256 blocks (1/CU instead of 0.5/CU).
__global__ __launch_bounds__(256) void gemm_o_kernel(
    const short* __restrict__ X, const short* __restrict__ W,
    const float* __restrict__ bias, float* __restrict__ outF)
{
    __shared__ short As[64 * 32], Bs[128 * 32];
    gemm_core<64, 0>(As, Bs, X, W, bias, 1.0f, outF, nullptr,
                     (int)(blockIdx.x >> 2) * 64, (int)(blockIdx.x & 3) * 128);
}

// ---------------------------------------------------------------------------
// RoPE on f16 K in place; per-block LDS sin/cos table (4 rows x 32 freqs).
// ---------------------------------------------------------------------------
__global__ __launch_bounds__(256) void rope_kernel(short* __restrict__ Kh)
{
    __shared__ float2 tbl[4][32];
    const int t = threadIdx.x;
    const int g = blockIdx.x * 256 + t;     // 524288 total (8192 rows x 64)
    if (t < 128) {
        int p = t >> 5, i = t & 31;
        int pos = (blockIdx.x * 4 + p) & 4095;
        float fr = expf((float)i * -0.28782313662425576f);
        float sv, cv;
        sincosf((float)pos * fr, &sv, &cv);
        tbl[p][i] = make_float2(cv, sv);
    }
    __syncthreads();

    int row = g >> 6;
    int c8  = (g & 63) * 8;
    size_t off = (size_t)row * 512 + c8;
    f16x8 hv = *(const f16x8*)&Kh[off];
    float x[8];
    #pragma unroll
    for (int j = 0; j < 8; ++j) x[j] = (float)hv[j];
    const int rl = row & 3;
    const int ib = (c8 & 63) >> 1;
    #pragma unroll
    for (int p = 0; p < 4; ++p) {
        float2 cs = tbl[rl][ib + p];
        float e = x[2 * p], o = x[2 * p + 1];
        x[2 * p]     = e * cs.x - o * cs.y;
        x[2 * p + 1] = o * cs.x + e * cs.y;
    }
    #pragma unroll
    for (int j = 0; j < 8; ++j) hv[j] = (f16)x[j];
    *(f16x8*)&Kh[off] = hv;
}

// ---------------------------------------------------------------------------
// MFMA flash attention, single-pass f16.
// Wave-private K staging via global_load_lds, now 4 KB/tile/wave ->
// FOUR parities in the same 64 KB LDS: stage 2 tiles ahead, V prefetched
// 1 iter ahead into a register double-buffer. Steady-state wait is
// vmcnt(8) (never drains to 0 in the loop). P packed RTZ-f16 via
// v_cvt_pkrtz; row sums via ones-column PV (truncation bias cancels).
// (256,2): register budget ~210 unified, do not raise (spills R5/R6/R10).
// ---------------------------------------------------------------------------
__global__ __launch_bounds__(256, 2) void attn_mfma_kernel(
    const short* __restrict__ Qh, const short* __restrict__ Kh,
    const short* __restrict__ Vfrag, short* __restrict__ AO)
{
    __shared__ char smem[65536];   // loop: wave*16KB (4 x 4KB parity)
                                   // after loop: Opart 4*64*33 f32 + Lpart

    const int tid  = threadIdx.x;
    const int wave = tid >> 6;
    const int lane = tid & 63;
    const int quad = lane >> 4;
    const int l15  = lane & 15;

    const int bh = blockIdx.x & 15;      // XCD-local: blk%8 == h under RR
    const int qt = blockIdx.x >> 4;
    const int b  = bh >> 3, h = bh & 7;
    const int qb = qt * 64;

    // ---- Q as B-fragments (all 64 q rows), f16, scale pre-folded ----
    f16x8 qf[4][2];
    #pragma unroll
    for (int tq = 0; tq < 4; ++tq)
        #pragma unroll
        for (int c = 0; c < 2; ++c)
            qf[tq][c] = *(const f16x8*)&Qh[((size_t)(b * 2048 + qb + tq * 16 + l15)) * 512
                                           + h * 64 + c * 32 + quad * 8];

    f32x4 o[4][4];    // [tq][dt] O partials over this wave's kv
    f32x4 l4[4];      // [tq] row sums (ones-column PV)
    #pragma unroll
    for (int i = 0; i < 4; ++i) {
        l4[i] = (f32x4){0.f, 0.f, 0.f, 0.f};
        #pragma unroll
        for (int j = 0; j < 4; ++j) o[i][j] = (f32x4){0.f, 0.f, 0.f, 0.f};
    }

    f16x8 vones;
    #pragma unroll
    for (int j = 0; j < 8; ++j) vones[j] = (f16)1.0f;

    // per-lane K global base (this wave's kv rows)
    const short* kp = Kh + ((size_t)(b * 4096 + wave * 16 + l15)) * 512
                      + h * 64 + quad * 8;
    const short* vbase = Vfrag + (size_t)(b * 8 + h) * 262144
                         + ((size_t)(wave * 4) * 64 + lane) * 8;

    // wave-private staging: parity p at +p*2048 shorts, frag f=s*2+c at
    // +f*512, lane reads at +lane*8.
    short* sw = (short*)smem + wave * 8192;   // 8192 shorts = 16 KB

#define STG(I2, P) {                                                         \
    const short* _src = kp + (size_t)(I2) * 65536;                           \
    short* _dst = sw + (P) * 2048;                                           \
    gload16(_src,              _dst);                                        \
    gload16(_src + 32,         _dst + 512);                                  \
    gload16(_src + 32768,      _dst + 1024);                                 \
    gload16(_src + 32768 + 32, _dst + 1536);                                 \
}

    // prologue: stage tiles 0,1; V(0) into vf0
    STG(0, 0); STG(1, 1);
    f16x8 vf0[4], vf1[4];
    #pragma unroll
    for (int dt = 0; dt < 4; ++dt) vf0[dt] = *(const f16x8*)(vbase + dt * 512);

    // NOTE: tail iterations intentionally prefetch V(32)/stage(32,33) from
    // adjacent workspace regions (allocated, never consumed) so the vmcnt
    // arithmetic stays uniform through the last iteration.
#define AITER(I, PAR, NPAR, VCUR, VNXT) {                                    \
    /* everything older than {V(I), stage(I+1)} (8 ops) is complete */       \
    asm volatile("s_waitcnt vmcnt(8)" ::: "memory");                         \
    const short* kb = sw + (PAR) * 2048;                                     \
    f16x8 k0[2], k1[2];                                                      \
    k0[0] = *(const f16x8*)(kb + lane * 8);                                  \
    k0[1] = *(const f16x8*)(kb + 512 + lane * 8);                            \
    k1[0] = *(const f16x8*)(kb + 1024 + lane * 8);                           \
    k1[1] = *(const f16x8*)(kb + 1536 + lane * 8);                           \
    {   const short* _vn = vbase + (size_t)((I) + 1) * 8192;                 \
        _Pragma("unroll")                                                    \
        for (int dt = 0; dt < 4; ++dt)                                       \
            VNXT[dt] = *(const f16x8*)(_vn + dt * 512); }                    \
    STG((I) + 2, NPAR);                                                      \
    f32x4 s0[4], s1[4];                                                      \
    _Pragma("unroll")                                                        \
    for (int t = 0; t < 4; ++t) {                                            \
        s0[t] = (f32x4){0.f, 0.f, 0.f, 0.f};                                 \
        s1[t] = (f32x4){0.f, 0.f, 0.f, 0.f};                                 \
    }                                                                        \
    __builtin_amdgcn_s_setprio(1);                                           \
    _Pragma("unroll")                                                        \
    for (int c = 0; c < 2; ++c)                                              \
        _Pragma("unroll")                                                    \
        for (int t = 0; t < 4; ++t) {                                        \
            s0[t] = MFMA16(k0[c], qf[t][c], s0[t]);                          \
            s1[t] = MFMA16(k1[c], qf[t][c], s1[t]);                          \
        }                                                                    \
    __builtin_amdgcn_s_setprio(0);                                           \
    _Pragma("unroll")                                                        \
    for (int t = 0; t < 4; ++t) {                                            \
        float e0 = exp2f(s0[t][0]), e1 = exp2f(s0[t][1]);                    \
        float e2 = exp2f(s0[t][2]), e3 = exp2f(s0[t][3]);                    \
        float e4 = exp2f(s1[t][0]), e5 = exp2f(s1[t][1]);                    \
        float e6 = exp2f(s1[t][2]), e7 = exp2f(s1[t][3]);                    \
        i32x4 pw;                                                            \
        pw.x = __builtin_bit_cast(int, __builtin_amdgcn_cvt_pkrtz(e0, e1));  \
        pw.y = __builtin_bit_cast(int, __builtin_amdgcn_cvt_pkrtz(e2, e3));  \
        pw.z = __builtin_bit_cast(int, __builtin_amdgcn_cvt_pkrtz(e4, e5));  \
        pw.w = __builtin_bit_cast(int, __builtin_amdgcn_cvt_pkrtz(e6, e7));  \
        f16x8 p8 = __builtin_bit_cast(f16x8, pw);                            \
        __builtin_amdgcn_s_setprio(1);                                       \
        _Pragma("unroll")                                                    \
        for (int dt = 0; dt < 4; ++dt)                                       \
            o[t][dt] = MFMA16(p8, VCUR[dt], o[t][dt]);                       \
        l4[t] = MFMA16(p8, vones, l4[t]);                                    \
        __builtin_amdgcn_s_setprio(0);                                       \
    }                                                                        \
}

    #pragma unroll 1
    for (int j = 0; j < 32; j += 4) {
        AITER(j + 0, 0, 2, vf0, vf1);
        AITER(j + 1, 1, 3, vf1, vf0);
        AITER(j + 2, 2, 0, vf0, vf1);
        AITER(j + 3, 3, 1, vf1, vf0);
    }
#undef AITER
#undef STG

    // drain in-flight tail DMAs before repurposing LDS
    asm volatile("s_waitcnt vmcnt(0)" ::: "memory");
    __syncthreads();
    float* Opart = (float*)smem;               // [4][64*33]
    float* Lpart = (float*)(smem + 33792);     // [4][64]

    // ---- two-pass cross-wave O reduction (pass 0: d 0..31, 1: 32..63) ----
    float inv_save[8];
    #pragma unroll
    for (int pass = 0; pass < 2; ++pass) {
        if (pass) __syncthreads();
        #pragma unroll
        for (int tq = 0; tq < 4; ++tq)
            #pragma unroll
            for (int dh = 0; dh < 2; ++dh) {
                int dt = pass * 2 + dh;
                #pragma unroll
                for (int r = 0; r < 4; ++r)
                    Opart[wave * (64 * 33) + (tq * 16 + quad * 4 + r) * 33 + dh * 16 + l15] = o[tq][dt][r];
            }
        if (pass == 0 && l15 == 0) {
            #pragma unroll
            for (int tq = 0; tq < 4; ++tq)
                #pragma unroll
                for (int r = 0; r < 4; ++r)
                    Lpart[wave * 64 + tq * 16 + quad * 4 + r] = l4[tq][r];
        }
        __syncthreads();
        #pragma unroll
        for (int r = 0; r < 8; ++r) {
            int qq = wave * 16 + r * 2 + (lane >> 5);
            int d  = lane & 31;
            float v = Opart[0 * (64 * 33) + qq * 33 + d] + Opart[1 * (64 * 33) + qq * 33 + d]
                    + Opart[2 * (64 * 33) + qq * 33 + d] + Opart[3 * (64 * 33) + qq * 33 + d];
            float inv;
            if (pass == 0) {
                float l = Lpart[qq] + Lpart[64 + qq] + Lpart[128 + qq] + Lpart[192 + qq];
                inv = 1.0f / l;
                inv_save[r] = inv;
            } else {
                inv = inv_save[r];
            }
            float val = v * inv;
            size_t oo = ((size_t)(b * 2048 + qb + qq)) * 512 + h * 64 + pass * 32 + d;
            AO[oo] = f2h(val);
        }
    }
}

// ---------------------------------------------------------------------------
extern "C" void kernel_launch(void* const* d_in, const int* in_sizes, int n_in,
                              void* d_out, int out_size, void* d_ws, size_t ws_size,
                              hipStream_t stream) {
    const float* q  = (const float*)d_in[0];
    const float* kv = (const float*)d_in[1];
    const float* Wq = (const float*)d_in[2];
    const float* bq = (const float*)d_in[3];
    const float* Wk = (const float*)d_in[4];
    const float* bk = (const float*)d_in[5];
    const float* Wv = (const float*)d_in[6];
    const float* bv = (const float*)d_in[7];
    const float* Wo = (const float*)d_in[8];
    const float* bo = (const float*)d_in[9];
    float* out = (float*)d_out;

    char* ws = (char*)d_ws;
    const size_t MB = 1024 * 1024;
    short* cq  = (short*)(ws + 0 * MB);    // 4 MB
    short* ckv = (short*)(ws + 4 * MB);    // 8 MB
    short* wq  = (short*)(ws + 12 * MB);   // 512 KB each
    short* wk  = wq + 262144;
    short* wv  = wk + 262144;
    short* wo  = wv + 262144;
    short* Qh  = (short*)(ws + 14 * MB);   // 4 MB
    short* Kh  = (short*)(ws + 18 * MB);   // 8 MB
    short* Vf  = (short*)(ws + 26 * MB);   // 8 MB
    short* AO  = (short*)(ws + 34 * MB);   // 4 MB

    // 0.125 (1/sqrt(Dh)) * log2(e), so attention exp is a bare exp2.
    const float qscale = 0.18033688011112043f;

    dim3 blk(256);
    convert_kernel<<<7168, blk, 0, stream>>>(
        q, kv, Wq, Wk, Wv, Wo, cq, ckv, wq, wk, wv, wo);

    fused_qkv_gemm_kernel<<<640, blk, 0, stream>>>(
        cq, ckv, wq, wk, wv, bq, bk, bv, qscale, Qh, Kh, Vf);

    rope_kernel<<<2048, blk, 0, stream>>>(Kh);

    attn_mfma_kernel<<<512, blk, 0, stream>>>(Qh, Kh, Vf, AO);

    gemm_o_kernel<<<256, blk, 0, stream>>>(AO, wo, bo, out);
}

// Round 2
// 166.062 us; speedup vs baseline: 1.5534x; 1.0580x over previous
//
#include <hip/hip_runtime.h>
#include <math.h>

typedef _Float16 f16;
typedef __attribute__((ext_vector_type(8))) f16 f16x8;
typedef __attribute__((ext_vector_type(4))) float f32x4;
typedef __attribute__((ext_vector_type(4))) int   i32x4;

__device__ __forceinline__ short f2h(float f) {      // RNE f32->f16, bits
    return __builtin_bit_cast(short, (f16)f);
}
__device__ __forceinline__ float h2f(short s) {
    return (float)__builtin_bit_cast(f16, s);
}

__device__ __forceinline__ void gload16(const void* g, void* l) {
    __builtin_amdgcn_global_load_lds(
        (const __attribute__((address_space(1))) unsigned int*)g,
        (__attribute__((address_space(3))) unsigned int*)l, 16, 0, 0);
}

#define MFMA16(A, B, C) __builtin_amdgcn_mfma_f32_16x16x32_f16(A, B, C, 0, 0, 0)
#define EXP2(x) __builtin_amdgcn_exp2f(x)    // raw v_exp_f32: softmax only needs
                                             // underflow-to-0, not libm denormal path

// ---------------------------------------------------------------------------
// fp32 -> single f16 conversion. Segments (float4 units): q 524288 |
// kv 1048576 | Wq,Wk,Wv,Wo 65536 each. Thread = one float4.
// ---------------------------------------------------------------------------
__global__ __launch_bounds__(256) void convert_kernel(
    const float* __restrict__ q, const float* __restrict__ kv,
    const float* __restrict__ Wq, const float* __restrict__ Wk,
    const float* __restrict__ Wv, const float* __restrict__ Wo,
    short* __restrict__ cq, short* __restrict__ ckv,
    short* __restrict__ wq, short* __restrict__ wk,
    short* __restrict__ wv, short* __restrict__ wo)
{
    int g = blockIdx.x * 256 + threadIdx.x;
    const float* src; short* dst; int local;
    if      (g <  524288) { src = q;  dst = cq;  local = g; }
    else if (g < 1572864) { src = kv; dst = ckv; local = g -  524288; }
    else if (g < 1638400) { src = Wq; dst = wq;  local = g - 1572864; }
    else if (g < 1703936) { src = Wk; dst = wk;  local = g - 1638400; }
    else if (g < 1769472) { src = Wv; dst = wv;  local = g - 1703936; }
    else                  { src = Wo; dst = wo;  local = g - 1769472; }
    float4 v = *(const float4*)(src + (size_t)local * 4);
    short4 hv; short* hp = (short*)&hv;
    hp[0] = f2h(v.x); hp[1] = f2h(v.y); hp[2] = f2h(v.z); hp[3] = f2h(v.w);
    *(short4*)(dst + (size_t)local * 4) = hv;
}

// ---------------------------------------------------------------------------
// Single-pass f16 GEMM core, 2-phase pipelined: double-buffered LDS,
// stage(k+1) issued BEFORE compute(k), one vmcnt(0)+barrier per step
// (drain covered by ds_read+MFMA). RT = rows per block (128 or 64),
// 128 cols, 4 waves (2x2), BK=32. EP: 0 fp32 | 1 f16 scaled | 2 V-frag.
// ---------------------------------------------------------------------------
template<int RT, int EP>
__device__ __forceinline__ void gemm_core(
    short* As, short* Bs,          // As: [2][RT*32], Bs: [2][128*32]
    const short* __restrict__ X, const short* __restrict__ W,
    const float* __restrict__ bias, float scale,
    float* __restrict__ outF, short* __restrict__ outH,
    int m0, int n0)
{
    const int tid  = threadIdx.x;
    const int wave = tid >> 6, lane = tid & 63;
    const int quad = lane >> 4, col = lane & 15;
    const int wy = wave >> 1, wx = wave & 1;
    constexpr int MT  = RT / 32;         // per-wave 16-row m-tiles
    constexpr int ASZ = RT * 32;         // shorts per A buffer

    f32x4 acc[MT][4];
    #pragma unroll
    for (int i = 0; i < MT; ++i)
        #pragma unroll
        for (int j = 0; j < 4; ++j) acc[i][j] = (f32x4){0.f, 0.f, 0.f, 0.f};

    int aoff[MT], boff[4];
    #pragma unroll
    for (int t = 0; t < MT; ++t)
        aoff[t] = (wy * (RT / 2) + t * 16 + col) * 32 + quad * 8;
    #pragma unroll
    for (int t = 0; t < 4; ++t)
        boff[t] = (wx * 64 + t * 16 + col) * 32 + quad * 8;

    const short* Abase = X + (size_t)m0 * 512;
    const short* Bbase = W + (size_t)n0 * 512;

#define STAGE_G(BUF, KB) {                                                   \
    _Pragma("unroll")                                                        \
    for (int i = 0; i < RT / 64; ++i) {                                      \
        int p = i * 256 + tid; int r = p >> 2, qq = p & 3;                   \
        gload16(Abase + (size_t)r * 512 + (KB) + qq * 8,                     \
                &As[(BUF) * ASZ + (i * 256 + wave * 64) * 8]);               \
    }                                                                        \
    _Pragma("unroll")                                                        \
    for (int i = 0; i < 2; ++i) {                                            \
        int p = i * 256 + tid; int r = p >> 2, qq = p & 3;                   \
        gload16(Bbase + (size_t)r * 512 + (KB) + qq * 8,                     \
                &Bs[(BUF) * 4096 + (i * 256 + wave * 64) * 8]);              \
    }                                                                        \
}

    STAGE_G(0, 0);
    asm volatile("s_waitcnt vmcnt(0)" ::: "memory");
    __syncthreads();

    for (int kb = 0; kb < 512; kb += 32) {
        const int cur = (kb >> 5) & 1;
        if (kb + 32 < 512) STAGE_G(cur ^ 1, kb + 32);   // issue-ahead
        f16x8 a[MT], b[4];
        #pragma unroll
        for (int t = 0; t < MT; ++t) a[t] = *(const f16x8*)&As[cur * ASZ + aoff[t]];
        #pragma unroll
        for (int t = 0; t < 4; ++t)  b[t] = *(const f16x8*)&Bs[cur * 4096 + boff[t]];
        #pragma unroll
        for (int tm = 0; tm < MT; ++tm)
            #pragma unroll
            for (int tn = 0; tn < 4; ++tn)
                acc[tm][tn] = MFMA16(a[tm], b[tn], acc[tm][tn]);
        asm volatile("s_waitcnt vmcnt(0)" ::: "memory");  // next stage landed
        __syncthreads();                                   // all reads of cur done
    }
#undef STAGE_G

    #pragma unroll
    for (int tn = 0; tn < 4; ++tn) {
        int ng = n0 + wx * 64 + tn * 16 + col;
        float bb = bias[ng];
        #pragma unroll
        for (int tm = 0; tm < MT; ++tm) {
            int mb = m0 + wy * (RT / 2) + tm * 16 + quad * 4;
            if constexpr (EP == 2) {
                // V-fragment order for attention PV B-operand.
                int bb_ = mb >> 12, kvg = mb & 4095;
                int tile = kvg >> 7, kv128 = kvg & 127;
                int t01 = (kv128 >> 6) & 1, sv = (kv128 >> 4) & 3, qd = (kv128 >> 2) & 3;
                int hh = ng >> 6, dd = ng & 63, dt = dd >> 4, d15 = dd & 15;
                size_t base = ((((size_t)((bb_ * 8 + hh) * 32 + tile) * 16)
                               + sv * 4 + dt) * 64 + qd * 16 + d15) * 8 + t01 * 4;
                short4 s4; short* sp = (short*)&s4;
                #pragma unroll
                for (int r = 0; r < 4; ++r) sp[r] = f2h(acc[tm][tn][r] + bb);
                *(short4*)&outH[base] = s4;
            } else if constexpr (EP == 1) {
                #pragma unroll
                for (int r = 0; r < 4; ++r)
                    outH[(size_t)(mb + r) * 512 + ng] =
                        f2h((acc[tm][tn][r] + bb) * scale);
            } else {
                #pragma unroll
                for (int r = 0; r < 4; ++r)
                    outF[(size_t)(mb + r) * 512 + ng] = acc[tm][tn][r] + bb;
            }
        }
    }
}

// Fused Q/K/V projections: blocks [0,128) Q | [128,384) K | [384,640) V.
__global__ __launch_bounds__(256) void fused_qkv_gemm_kernel(
    const short* __restrict__ cq, const short* __restrict__ ckv,
    const short* __restrict__ wq, const short* __restrict__ wk,
    const short* __restrict__ wv,
    const float* __restrict__ bq, const float* __restrict__ bk,
    const float* __restrict__ bv, float qscale,
    short* __restrict__ Qh, short* __restrict__ Kh, short* __restrict__ Vf)
{
    __shared__ short As[2 * 128 * 32], Bs[2 * 128 * 32];
    int bi = blockIdx.x;
    if (bi < 128) {
        gemm_core<128, 1>(As, Bs, cq, wq, bq, qscale, nullptr, Qh,
                          (bi >> 2) * 128, (bi & 3) * 128);
    } else if (bi < 384) {
        bi -= 128;
        gemm_core<128, 1>(As, Bs, ckv, wk, bk, 1.0f, nullptr, Kh,
                          (bi >> 2) * 128, (bi & 3) * 128);
    } else {
        bi -= 384;
        gemm_core<128, 2>(As, Bs, ckv, wv, bv, 1.0f, nullptr, Vf,
                          (bi >> 2) * 128, (bi & 3) * 128);
    }
}

// O-projection: 64-row tiles -> 256 blocks.
__global__ __launch_bounds__(256) void gemm_o_kernel(
    const short* __restrict__ X, const short* __restrict__ W,
    const float* __restrict__ bias, float* __restrict__ outF)
{
    __shared__ short As[2 * 64 * 32], Bs[2 * 128 * 32];
    gemm_core<64, 0>(As, Bs, X, W, bias, 1.0f, outF, nullptr,
                     (int)(blockIdx.x >> 2) * 64, (int)(blockIdx.x & 3) * 128);
}

// ---------------------------------------------------------------------------
// RoPE on f16 K in place; per-block LDS sin/cos table (4 rows x 32 freqs).
// ---------------------------------------------------------------------------
__global__ __launch_bounds__(256) void rope_kernel(short* __restrict__ Kh)
{
    __shared__ float2 tbl[4][32];
    const int t = threadIdx.x;
    const int g = blockIdx.x * 256 + t;     // 524288 total (8192 rows x 64)
    if (t < 128) {
        int p = t >> 5, i = t & 31;
        int pos = (blockIdx.x * 4 + p) & 4095;
        float fr = expf((float)i * -0.28782313662425576f);
        float sv, cv;
        sincosf((float)pos * fr, &sv, &cv);
        tbl[p][i] = make_float2(cv, sv);
    }
    __syncthreads();

    int row = g >> 6;
    int c8  = (g & 63) * 8;
    size_t off = (size_t)row * 512 + c8;
    f16x8 hv = *(const f16x8*)&Kh[off];
    float x[8];
    #pragma unroll
    for (int j = 0; j < 8; ++j) x[j] = (float)hv[j];
    const int rl = row & 3;
    const int ib = (c8 & 63) >> 1;
    #pragma unroll
    for (int p = 0; p < 4; ++p) {
        float2 cs = tbl[rl][ib + p];
        float e = x[2 * p], o = x[2 * p + 1];
        x[2 * p]     = e * cs.x - o * cs.y;
        x[2 * p + 1] = o * cs.x + e * cs.y;
    }
    #pragma unroll
    for (int j = 0; j < 8; ++j) hv[j] = (f16)x[j];
    *(f16x8*)&Kh[off] = hv;
}

// ---------------------------------------------------------------------------
// MFMA flash attention, single-pass f16, PURE REGISTER double-buffering:
// K and V go global->VGPR directly (wave-private data; LDS staging added a
// DMA-drain + ds_read + bank conflicts for zero sharing). Compiler emits
// counted vmcnt for the reg loads; prefetch distance = 1 full iteration.
// Body order: LDK(next) -> FIN(prev) -> LDV(next) -> QK(cur) keeps one live
// s-set (reg peak ~230 under the (256,2) cap). zero4 as MFMA C-operand
// kills per-iter acc init. exp2 is raw v_exp_f32. LDS = epilogue only.
// ---------------------------------------------------------------------------
__global__ __launch_bounds__(256, 2) void attn_mfma_kernel(
    const short* __restrict__ Qh, const short* __restrict__ Kh,
    const short* __restrict__ Vfrag, short* __restrict__ AO)
{
    __shared__ char smem[34816];   // epilogue: Opart 4*64*33 f32 + Lpart

    const int tid  = threadIdx.x;
    const int wave = tid >> 6;
    const int lane = tid & 63;
    const int quad = lane >> 4;
    const int l15  = lane & 15;

    const int bh = blockIdx.x & 15;      // XCD-local: blk%8 == h under RR
    const int qt = blockIdx.x >> 4;
    const int b  = bh >> 3, h = bh & 7;
    const int qb = qt * 64;

    // ---- Q as B-fragments (all 64 q rows), f16, scale pre-folded ----
    f16x8 qf[4][2];
    #pragma unroll
    for (int tq = 0; tq < 4; ++tq)
        #pragma unroll
        for (int c = 0; c < 2; ++c)
            qf[tq][c] = *(const f16x8*)&Qh[((size_t)(b * 2048 + qb + tq * 16 + l15)) * 512
                                           + h * 64 + c * 32 + quad * 8];

    f32x4 o[4][4];    // [tq][dt] O partials over this wave's kv
    f32x4 l4[4];      // [tq] row sums (ones-column PV)
    #pragma unroll
    for (int i = 0; i < 4; ++i) {
        l4[i] = (f32x4){0.f, 0.f, 0.f, 0.f};
        #pragma unroll
        for (int j = 0; j < 4; ++j) o[i][j] = (f32x4){0.f, 0.f, 0.f, 0.f};
    }

    const f32x4 zero4 = (f32x4){0.f, 0.f, 0.f, 0.f};
    f16x8 vones;
    #pragma unroll
    for (int j = 0; j < 8; ++j) vones[j] = (f16)1.0f;

    // per-lane K/V global bases (this wave's kv rows)
    const short* kp = Kh + ((size_t)(b * 4096 + wave * 16 + l15)) * 512
                      + h * 64 + quad * 8;
    const short* vbase = Vfrag + (size_t)(b * 8 + h) * 262144
                         + ((size_t)(wave * 4) * 64 + lane) * 8;

    // K(I) regs: [k0 c0, k0 c1, k1 c0, k1 c1]
#define LDK(DST, I) { const short* _k = kp + (size_t)(I) * 65536;            \
    DST[0] = *(const f16x8*)(_k);                                            \
    DST[1] = *(const f16x8*)(_k + 32);                                       \
    DST[2] = *(const f16x8*)(_k + 32768);                                    \
    DST[3] = *(const f16x8*)(_k + 32800); }
#define LDV(DST, I) { const short* _v = vbase + (size_t)(I) * 8192;          \
    DST[0] = *(const f16x8*)(_v);                                            \
    DST[1] = *(const f16x8*)(_v + 512);                                      \
    DST[2] = *(const f16x8*)(_v + 1024);                                     \
    DST[3] = *(const f16x8*)(_v + 1536); }

#define QK(KC) {                                                             \
    __builtin_amdgcn_s_setprio(1);                                           \
    _Pragma("unroll")                                                        \
    for (int t = 0; t < 4; ++t) {                                            \
        s0[t] = MFMA16(KC[0], qf[t][0], zero4);                              \
        s0[t] = MFMA16(KC[1], qf[t][1], s0[t]);                              \
        s1[t] = MFMA16(KC[2], qf[t][0], zero4);                              \
        s1[t] = MFMA16(KC[3], qf[t][1], s1[t]);                              \
    }                                                                        \
    __builtin_amdgcn_s_setprio(0); }

#define FIN(VP) {                                                            \
    _Pragma("unroll")                                                        \
    for (int t = 0; t < 4; ++t) {                                            \
        float e0 = EXP2(s0[t][0]), e1 = EXP2(s0[t][1]);                      \
        float e2 = EXP2(s0[t][2]), e3 = EXP2(s0[t][3]);                      \
        float e4 = EXP2(s1[t][0]), e5 = EXP2(s1[t][1]);                      \
        float e6 = EXP2(s1[t][2]), e7 = EXP2(s1[t][3]);                      \
        i32x4 pw;                                                            \
        pw.x = __builtin_bit_cast(int, __builtin_amdgcn_cvt_pkrtz(e0, e1));  \
        pw.y = __builtin_bit_cast(int, __builtin_amdgcn_cvt_pkrtz(e2, e3));  \
        pw.z = __builtin_bit_cast(int, __builtin_amdgcn_cvt_pkrtz(e4, e5));  \
        pw.w = __builtin_bit_cast(int, __builtin_amdgcn_cvt_pkrtz(e6, e7));  \
        f16x8 p8 = __builtin_bit_cast(f16x8, pw);                            \
        __builtin_amdgcn_s_setprio(1);                                       \
        _Pragma("unroll")                                                    \
        for (int dt = 0; dt < 4; ++dt)                                       \
            o[t][dt] = MFMA16(p8, VP[dt], o[t][dt]);                         \
        l4[t] = MFMA16(p8, vones, l4[t]);                                    \
        __builtin_amdgcn_s_setprio(0);                                       \
    } }

    // BODY(I): finish iter I-1, compute QK(I), prefetch K/V(I+1).
    // NOTE: I=31 prefetches tile 32 from adjacent allocated workspace
    // (never consumed) so the pattern stays uniform.
#define BODY(I, KC, KN, VP) {                                                \
    LDK(KN, (I) + 1);                                                        \
    FIN(VP);                                                                 \
    LDV(VP, (I) + 1);                                                        \
    QK(KC); }

    f16x8 kA[4], kB[4], vA[4], vB[4];
    f32x4 s0[4], s1[4];

    // prologue: K0,V0,K1,V1 in flight; QK(0)
    LDK(kA, 0); LDV(vA, 0); LDK(kB, 1); LDV(vB, 1);
    QK(kA);

    #pragma unroll 1
    for (int j = 1; j < 31; j += 2) {
        BODY(j,     kB, kA, vA);
        BODY(j + 1, kA, kB, vB);
    }
    BODY(31, kB, kA, vA);
    FIN(vB);          // iter 31: s = QK(31), V(31) in vB

#undef BODY
#undef FIN
#undef QK
#undef LDV
#undef LDK

    float* Opart = (float*)smem;               // [4][64*33]
    float* Lpart = (float*)(smem + 33792);     // [4][64]

    // ---- two-pass cross-wave O reduction (pass 0: d 0..31, 1: 32..63) ----
    float inv_save[8];
    #pragma unroll
    for (int pass = 0; pass < 2; ++pass) {
        if (pass) __syncthreads();
        #pragma unroll
        for (int tq = 0; tq < 4; ++tq)
            #pragma unroll
            for (int dh = 0; dh < 2; ++dh) {
                int dt = pass * 2 + dh;
                #pragma unroll
                for (int r = 0; r < 4; ++r)
                    Opart[wave * (64 * 33) + (tq * 16 + quad * 4 + r) * 33 + dh * 16 + l15] = o[tq][dt][r];
            }
        if (pass == 0 && l15 == 0) {
            #pragma unroll
            for (int tq = 0; tq < 4; ++tq)
                #pragma unroll
                for (int r = 0; r < 4; ++r)
                    Lpart[wave * 64 + tq * 16 + quad * 4 + r] = l4[tq][r];
        }
        __syncthreads();
        #pragma unroll
        for (int r = 0; r < 8; ++r) {
            int qq = wave * 16 + r * 2 + (lane >> 5);
            int d  = lane & 31;
            float v = Opart[0 * (64 * 33) + qq * 33 + d] + Opart[1 * (64 * 33) + qq * 33 + d]
                    + Opart[2 * (64 * 33) + qq * 33 + d] + Opart[3 * (64 * 33) + qq * 33 + d];
            float inv;
            if (pass == 0) {
                float l = Lpart[qq] + Lpart[64 + qq] + Lpart[128 + qq] + Lpart[192 + qq];
                inv = 1.0f / l;
                inv_save[r] = inv;
            } else {
                inv = inv_save[r];
            }
            float val = v * inv;
            size_t oo = ((size_t)(b * 2048 + qb + qq)) * 512 + h * 64 + pass * 32 + d;
            AO[oo] = f2h(val);
        }
    }
}

// ---------------------------------------------------------------------------
extern "C" void kernel_launch(void* const* d_in, const int* in_sizes, int n_in,
                              void* d_out, int out_size, void* d_ws, size_t ws_size,
                              hipStream_t stream) {
    const float* q  = (const float*)d_in[0];
    const float* kv = (const float*)d_in[1];
    const float* Wq = (const float*)d_in[2];
    const float* bq = (const float*)d_in[3];
    const float* Wk = (const float*)d_in[4];
    const float* bk = (const float*)d_in[5];
    const float* Wv = (const float*)d_in[6];
    const float* bv = (const float*)d_in[7];
    const float* Wo = (const float*)d_in[8];
    const float* bo = (const float*)d_in[9];
    float* out = (float*)d_out;

    char* ws = (char*)d_ws;
    const size_t MB = 1024 * 1024;
    short* cq  = (short*)(ws + 0 * MB);    // 4 MB
    short* ckv = (short*)(ws + 4 * MB);    // 8 MB
    short* wq  = (short*)(ws + 12 * MB);   // 512 KB each
    short* wk  = wq + 262144;
    short* wv  = wk + 262144;
    short* wo  = wv + 262144;
    short* Qh  = (short*)(ws + 14 * MB);   // 4 MB
    short* Kh  = (short*)(ws + 18 * MB);   // 8 MB (tail prefetch spills into Vf: allocated)
    short* Vf  = (short*)(ws + 26 * MB);   // 8 MB (tail prefetch spills into AO: allocated)
    short* AO  = (short*)(ws + 34 * MB);   // 4 MB

    // 0.125 (1/sqrt(Dh)) * log2(e), so attention exp is a bare exp2.
    const float qscale = 0.18033688011112043f;

    dim3 blk(256);
    convert_kernel<<<7168, blk, 0, stream>>>(
        q, kv, Wq, Wk, Wv, Wo, cq, ckv, wq, wk, wv, wo);

    fused_qkv_gemm_kernel<<<640, blk, 0, stream>>>(
        cq, ckv, wq, wk, wv, bq, bk, bv, qscale, Qh, Kh, Vf);

    rope_kernel<<<2048, blk, 0, stream>>>(Kh);

    attn_mfma_kernel<<<512, blk, 0, stream>>>(Qh, Kh, Vf, AO);

    gemm_o_kernel<<<256, blk, 0, stream>>>(AO, wo, bo, out);
}